// Round 11
// baseline (597.052 us; speedup 1.0000x reference)
//
#include <hip/hip_runtime.h>

#define BB 32
#define SS 512
#define EE 512
#define NHH 2
#define HDD 256
#define E3 1536
#define NT 24
#define MR (BB*SS)   // 16384

typedef _Float16 half8  __attribute__((ext_vector_type(8)));
typedef _Float16 half4v __attribute__((ext_vector_type(4)));
typedef float    f32x4  __attribute__((ext_vector_type(4)));
typedef unsigned int u32;

// scalar (SGPR) lane broadcast — index MUST be wave-uniform (constant).
__device__ __forceinline__ float rl(float v, int l) {
    return __int_as_float(__builtin_amdgcn_readlane(__float_as_int(v), l));
}

// packed hi/lo fp16 split of fp32: u32 = h | (l<<16), RNE both ways.
__device__ __forceinline__ u32 packhl(float v) {
    _Float16 h = (_Float16)v;
    _Float16 l = (_Float16)(v - (float)h);
    unsigned short hb, lb;
    __builtin_memcpy(&hb, &h, 2);
    __builtin_memcpy(&lb, &l, 2);
    return (u32)hb | ((u32)lb << 16);
}
__device__ __forceinline__ _Float16 hl_lo(u32 u) {
    unsigned short s = (unsigned short)(u & 0xFFFFu);
    _Float16 f; __builtin_memcpy(&f, &s, 2); return f;
}
__device__ __forceinline__ _Float16 hl_hi(u32 u) {
    unsigned short s = (unsigned short)(u >> 16);
    _Float16 f; __builtin_memcpy(&f, &s, 2); return f;
}

// =====================================================================
// split_pack: fp32 tensor -> packed hl32, elementwise.
// =====================================================================
__global__ __launch_bounds__(256) void split_pack(
    const float* __restrict__ in, u32* __restrict__ out)
{
    const size_t i = ((size_t)blockIdx.x * 256 + threadIdx.x) * 4;
    float4 v = *(const float4*)(in + i);
    uint4 o;
    o.x = packhl(v.x); o.y = packhl(v.y); o.z = packhl(v.z); o.w = packhl(v.w);
    *(uint4*)(out + i) = o;
}

// =====================================================================
// fp32-accurate GEMM via fp16 3-product MFMA split (Ootomo), operands
// pre-split into packed hl32 (produced once per tensor; staging is
// pure copy + v_perm unpack — no cvt in the K-loop).
// 128x128 tile, 256 thr = 2x2 waves, 4x4 tiles of mfma 16x16x32 f16.
// BFMT: 0 = B fp32 N x K (weights; cvt staging, reused -> amortized)
//       1 = B packed N x K      2 = B packed K x N (V)
// EPACK: 0 = C fp32   1 = C packed hl32
// =====================================================================
template<int BFMT, int EPACK>
__global__ __launch_bounds__(256) void mfma_gemm_p(
    const u32* __restrict__ Ap, int lda, long sAhi, long sAlo, int zA,
    const void* __restrict__ Bp, int ldb, long sBhi, long sBlo, int zB,
    const float* __restrict__ bias,
    void* __restrict__ C, int ldc, long sChi, long sClo, int zC,
    int K, int relu)
{
    __shared__ __align__(16) _Float16 sAh[8*640];
    __shared__ __align__(16) _Float16 sAl[8*640];
    __shared__ __align__(16) _Float16 sBh[8*640];
    __shared__ __align__(16) _Float16 sBl[8*640];

    const int t = threadIdx.x;
    const int z = blockIdx.z;
    const int za = zA + z, zb = zB + z, zc = zC + z;
    const u32* Ab = Ap + (size_t)(za>>1)*sAhi + (size_t)(za&1)*sAlo
                       + (size_t)blockIdx.y*128*lda;
    const size_t boff = (size_t)(zb>>1)*sBhi + (size_t)(zb&1)*sBlo
                      + (BFMT == 2 ? (size_t)blockIdx.x*128
                                   : (size_t)blockIdx.x*128*ldb);
    const float* Bf = (const float*)Bp + boff;   // BFMT==0
    const u32*   Bu = (const u32*)Bp + boff;     // BFMT==1,2

    const int wv = t >> 6, lane = t & 63;
    const int wm = wv >> 1, wn = wv & 1;
    const int lm = lane & 15, lq = lane >> 4;

    f32x4 acc[4][4];
#pragma unroll
    for (int i = 0; i < 4; ++i)
#pragma unroll
        for (int j = 0; j < 4; ++j) acc[i][j] = (f32x4){0.f,0.f,0.f,0.f};

    const int r8 = t >> 3;          // 0..31 staging row base (A, B0/B1)
    const int kc = (t & 7) * 4;     // 0..28 staging k chunk (elems)
    const int vk  = t >> 3;         // B2: k row 0..31
    const int vns = (t & 7) * 16;   // B2: n segment 0..112

    for (int k0 = 0; k0 < K; k0 += 32) {
        uint4 ga[4]; float4 gbf[4]; uint4 gbu[4]; u32 vv[16];
#pragma unroll
        for (int i = 0; i < 4; ++i)
            ga[i] = *(const uint4*)(Ab + (size_t)(r8 + 32*i)*lda + k0 + kc);
        if (BFMT == 0) {
#pragma unroll
            for (int i = 0; i < 4; ++i)
                gbf[i] = *(const float4*)(Bf + (size_t)(r8 + 32*i)*ldb + k0 + kc);
        } else if (BFMT == 1) {
#pragma unroll
            for (int i = 0; i < 4; ++i)
                gbu[i] = *(const uint4*)(Bu + (size_t)(r8 + 32*i)*ldb + k0 + kc);
        } else {
#pragma unroll
            for (int jj = 0; jj < 4; ++jj) {
                uint4 u = *(const uint4*)(Bu + (size_t)(k0 + vk)*ldb + vns + jj*4);
                vv[jj*4+0]=u.x; vv[jj*4+1]=u.y; vv[jj*4+2]=u.z; vv[jj*4+3]=u.w;
            }
        }
        __syncthreads();   // previous iteration's fragment reads complete
#pragma unroll
        for (int i = 0; i < 4; ++i) {
            const int row  = r8 + 32*i;
            const int base = (row >> 4)*640 + (row & 15)*40 + kc;
            uint4 u = ga[i];
            uint2 hs, ls;
            hs.x = __builtin_amdgcn_perm(u.y, u.x, 0x05040100u);
            hs.y = __builtin_amdgcn_perm(u.w, u.z, 0x05040100u);
            ls.x = __builtin_amdgcn_perm(u.y, u.x, 0x07060302u);
            ls.y = __builtin_amdgcn_perm(u.w, u.z, 0x07060302u);
            *(uint2*)&sAh[base] = hs;
            *(uint2*)&sAl[base] = ls;
        }
        if (BFMT == 0) {
#pragma unroll
            for (int i = 0; i < 4; ++i) {
                const int row  = r8 + 32*i;
                const int base = (row >> 4)*640 + (row & 15)*40 + kc;
                float4 b = gbf[i];
                _Float16 h0 = (_Float16)b.x, h1 = (_Float16)b.y,
                         h2 = (_Float16)b.z, h3 = (_Float16)b.w;
                _Float16 l0 = (_Float16)(b.x - (float)h0),
                         l1 = (_Float16)(b.y - (float)h1),
                         l2 = (_Float16)(b.z - (float)h2),
                         l3 = (_Float16)(b.w - (float)h3);
                *(half4v*)&sBh[base] = (half4v){h0,h1,h2,h3};
                *(half4v*)&sBl[base] = (half4v){l0,l1,l2,l3};
            }
        } else if (BFMT == 1) {
#pragma unroll
            for (int i = 0; i < 4; ++i) {
                const int row  = r8 + 32*i;
                const int base = (row >> 4)*640 + (row & 15)*40 + kc;
                uint4 u = gbu[i];
                uint2 hs, ls;
                hs.x = __builtin_amdgcn_perm(u.y, u.x, 0x05040100u);
                hs.y = __builtin_amdgcn_perm(u.w, u.z, 0x05040100u);
                ls.x = __builtin_amdgcn_perm(u.y, u.x, 0x07060302u);
                ls.y = __builtin_amdgcn_perm(u.w, u.z, 0x07060302u);
                *(uint2*)&sBh[base] = hs;
                *(uint2*)&sBl[base] = ls;
            }
        } else {
            const int vt = (vns >> 4) * 640;
#pragma unroll
            for (int e = 0; e < 16; ++e) {
                const int base = vt + ((vns + e) & 15)*40 + vk;
                sBh[base] = hl_lo(vv[e]);
                sBl[base] = hl_hi(vv[e]);
            }
        }
        __syncthreads();

        half8 bhf[4], blf[4];
#pragma unroll
        for (int j = 0; j < 4; ++j) {
            const int tb = (wn*4 + j)*640 + lm*40 + lq*8;
            bhf[j] = *(const half8*)&sBh[tb];
            blf[j] = *(const half8*)&sBl[tb];
        }
#pragma unroll
        for (int i = 0; i < 4; ++i) {
            const int ta = (wm*4 + i)*640 + lm*40 + lq*8;
            half8 ah = *(const half8*)&sAh[ta];
            half8 al = *(const half8*)&sAl[ta];
#pragma unroll
            for (int j = 0; j < 4; ++j) {
                acc[i][j] = __builtin_amdgcn_mfma_f32_16x16x32_f16(ah, bhf[j], acc[i][j], 0, 0, 0);
                acc[i][j] = __builtin_amdgcn_mfma_f32_16x16x32_f16(al, bhf[j], acc[i][j], 0, 0, 0);
                acc[i][j] = __builtin_amdgcn_mfma_f32_16x16x32_f16(ah, blf[j], acc[i][j], 0, 0, 0);
            }
        }
    }

    // epilogue: C/D layout col = lane&15, row = quad*4 + reg
    const size_t coff = (size_t)(zc>>1)*sChi + (size_t)(zc&1)*sClo;
    float* Cf = (float*)C + coff;
    u32*   Cu = (u32*)C + coff;
#pragma unroll
    for (int j = 0; j < 4; ++j) {
        const int col = blockIdx.x*128 + (wn*4 + j)*16 + lm;
        const float bj = bias ? bias[col] : 0.f;
#pragma unroll
        for (int i = 0; i < 4; ++i) {
            const int row0 = blockIdx.y*128 + (wm*4 + i)*16 + lq*4;
#pragma unroll
            for (int r = 0; r < 4; ++r) {
                float v = acc[i][j][r] + bj;
                if (relu) v = fmaxf(v, 0.f);
                if (EPACK) Cu[(size_t)(row0 + r)*ldc + col] = packhl(v);
                else       Cf[(size_t)(row0 + r)*ldc + col] = v;
            }
        }
    }
}

// =====================================================================
// Row softmax over fp32 scores; writes packed hl32 P in place.
// =====================================================================
__global__ __launch_bounds__(256) void softmax_split(float* __restrict__ scores)
{
    const int w    = threadIdx.x >> 6;
    const int lane = threadIdx.x & 63;
    const size_t row = (size_t)blockIdx.x * 4 + w;
    float* p = scores + row * SS + lane * 8;
    float4 v0 = *(float4*)(p);
    float4 v1 = *(float4*)(p + 4);
    const float scale = 0.0625f;
    float m = fmaxf(fmaxf(fmaxf(v0.x, v0.y), fmaxf(v0.z, v0.w)),
                    fmaxf(fmaxf(v1.x, v1.y), fmaxf(v1.z, v1.w)));
#pragma unroll
    for (int off = 32; off >= 1; off >>= 1) m = fmaxf(m, __shfl_xor(m, off));
    v0.x = __expf((v0.x - m) * scale); v0.y = __expf((v0.y - m) * scale);
    v0.z = __expf((v0.z - m) * scale); v0.w = __expf((v0.w - m) * scale);
    v1.x = __expf((v1.x - m) * scale); v1.y = __expf((v1.y - m) * scale);
    v1.z = __expf((v1.z - m) * scale); v1.w = __expf((v1.w - m) * scale);
    float sum = v0.x + v0.y + v0.z + v0.w + v1.x + v1.y + v1.z + v1.w;
#pragma unroll
    for (int off = 32; off >= 1; off >>= 1) sum += __shfl_xor(sum, off);
    float inv = 1.f / sum;
    uint4 o0, o1;
    o0.x = packhl(v0.x*inv); o0.y = packhl(v0.y*inv);
    o0.z = packhl(v0.z*inv); o0.w = packhl(v0.w*inv);
    o1.x = packhl(v1.x*inv); o1.y = packhl(v1.y*inv);
    o1.z = packhl(v1.z*inv); o1.w = packhl(v1.w*inv);
    u32* up = (u32*)(scores + row * SS) + lane * 8;
    *(uint4*)(up)     = o0;
    *(uint4*)(up + 4) = o1;
}

// =====================================================================
// CRF emissions: fc[row][j] = dot(dec[row], crf_w[j]) + crf_b[j]
// =====================================================================
__global__ __launch_bounds__(192) void fc_crf_kernel(
    const float* __restrict__ dec, const float* __restrict__ W,
    const float* __restrict__ bias, float* __restrict__ out)
{
    __shared__ __align__(16) float Ws[NT][516];
    for (int i = threadIdx.x; i < NT*128; i += 192) {
        int j = i >> 7, c = (i & 127) * 4;
        *(float4*)&Ws[j][c] = *(const float4*)(W + (size_t)j*EE + c);
    }
    __syncthreads();
    const int t = threadIdx.x;
    const int rloc = t / NT;
    const int j = t - rloc * NT;
    const int row = blockIdx.x * 8 + rloc;
    const float4* a = (const float4*)(dec + (size_t)row * EE);
    float acc = 0.f;
#pragma unroll 4
    for (int i = 0; i < 128; ++i) {
        float4 x = a[i];
        float4 y = *(const float4*)&Ws[j][i*4];
        acc += x.x*y.x + x.y*y.y + x.z*y.z + x.w*y.w;
    }
    out[(size_t)row * NT + j] = acc + bias[j];
}

// =====================================================================
// CRF + seg, 64-thread blocks (round-9/10 structure; serial legs are
// dependency-chain-bound — staging experiments r9/r10 showed memory is
// not the limiter, so left as-is this round).
// =====================================================================
__global__ __launch_bounds__(64, 1) void crf_seg_kernel(
    const float* __restrict__ fc, const int* __restrict__ labels,
    const float* __restrict__ start_t, const float* __restrict__ end_t,
    const float* __restrict__ trans, const float* __restrict__ dec,
    const float* __restrict__ ent_w, const float* __restrict__ ent_b,
    float* __restrict__ num, float* __restrict__ den,
    float* __restrict__ crf_out, float* __restrict__ segout)
{
    __shared__ __align__(16) float fc_lds[SS*NT];     // 48 KB
    __shared__ unsigned char hist[(SS-1)*NT];         // 12 KB

    const int blk  = blockIdx.x;
    const int lane = threadIdx.x;

    if (blk >= 96) {
        const int row = blk - 96;
        const float4* a  = (const float4*)(dec + (size_t)row * EE);
        const float4* w0 = (const float4*)(ent_w);
        const float4* w1 = (const float4*)(ent_w + EE);
        float acc0 = 0.f, acc1 = 0.f;
#pragma unroll
        for (int i = 0; i < 2; ++i) {
            int idx = lane * 2 + i;
            float4 x = a[idx];
            float4 u = w0[idx];
            float4 v = w1[idx];
            acc0 += x.x*u.x + x.y*u.y + x.z*u.z + x.w*u.w;
            acc1 += x.x*v.x + x.y*v.y + x.z*v.z + x.w*v.w;
        }
#pragma unroll
        for (int off = 32; off >= 1; off >>= 1) {
            acc0 += __shfl_xor(acc0, off);
            acc1 += __shfl_xor(acc1, off);
        }
        if (lane == 0) {
            float l0 = acc0 + ent_b[0];
            float l1 = acc1 + ent_b[1];
            float m  = fmaxf(l0, l1);
            float lse = m + __logf(__expf(l0 - m) + __expf(l1 - m));
            segout[(size_t)row*2 + 0] = l0 - lse;
            segout[(size_t)row*2 + 1] = l1 - lse;
        }
        return;
    }

    const int role = blk >> 5;          // 0=forward, 1=viterbi, 2=numerator
    const int b    = blk & 31;
    const float* fcb = fc + (size_t)b * SS * NT;

    if (role == 2) {
        float acc = 0.f;
        for (int s = 1 + lane; s < SS; s += 64) {
            int prev = labels[b*SS + s - 1];
            int cur  = labels[b*SS + s];
            acc += trans[prev*NT + cur] + fcb[(size_t)s*NT + cur];
        }
        if (lane == 0) {
            int l0 = labels[b*SS];
            acc += start_t[l0] + fcb[l0] + end_t[labels[b*SS + SS - 1]];
        }
#pragma unroll
        for (int off = 32; off >= 1; off >>= 1) acc += __shfl_xor(acc, off);
        if (lane == 0) num[b] = acc;
        return;
    }

#pragma unroll
    for (int i = 0; i < SS*NT/256; ++i) {
        const int idx = i*256 + lane*4;
        *(float4*)&fc_lds[idx] = *(const float4*)(fcb + idx);
    }
    __syncthreads();

    const int j = (lane < NT) ? lane : 0;
    float sc = start_t[j] + fc_lds[j];

    if (role == 0) {
        float etr[NT];
#pragma unroll
        for (int i = 0; i < NT; ++i) etr[i] = __expf(trans[i*NT + j]);
        float em_next = fc_lds[NT + j];
        for (int s = 1; s < SS; ++s) {
            float em = em_next;
            int snx = (s + 1 < SS) ? s + 1 : s;
            em_next = fc_lds[snx * NT + j];
            const float m  = __builtin_amdgcn_readfirstlane(sc);
            const float eo = __expf(sc - m);
            float a0 = 0.f, a1 = 0.f, a2 = 0.f, a3 = 0.f;
#pragma unroll
            for (int i = 0; i < NT; i += 4) {
                a0 = fmaf(rl(eo, i+0), etr[i+0], a0);
                a1 = fmaf(rl(eo, i+1), etr[i+1], a1);
                a2 = fmaf(rl(eo, i+2), etr[i+2], a2);
                a3 = fmaf(rl(eo, i+3), etr[i+3], a3);
            }
            sc = m + __logf((a0 + a1) + (a2 + a3)) + em;
        }
        float v = (lane < NT) ? sc + end_t[j] : -1e30f;
        float m2 = v;
#pragma unroll
        for (int off = 32; off >= 1; off >>= 1) m2 = fmaxf(m2, __shfl_xor(m2, off));
        float e = (lane < NT) ? __expf(v - m2) : 0.f;
#pragma unroll
        for (int off = 32; off >= 1; off >>= 1) e += __shfl_xor(e, off);
        if (lane == 0) den[b] = m2 + __logf(e);
    } else {
        float trC[NT];
#pragma unroll
        for (int i = 0; i < NT; ++i) trC[i] = trans[i*NT + j];
        float em_next = fc_lds[NT + j];
        for (int s = 1; s < SS; ++s) {
            float em = em_next;
            int snx = (s + 1 < SS) ? s + 1 : s;
            em_next = fc_lds[snx * NT + j];
            float tv[NT]; int ti[NT];
#pragma unroll
            for (int i = 0; i < NT; ++i) { tv[i] = rl(sc, i) + trC[i]; ti[i] = i; }
#pragma unroll
            for (int st = 1; st < NT; st <<= 1)
#pragma unroll
                for (int i = 0; i + st < NT; i += 2*st)
                    if (tv[i+st] > tv[i]) { tv[i] = tv[i+st]; ti[i] = ti[i+st]; }
            sc = tv[0] + em;
            if (lane < NT) hist[(s-1)*NT + lane] = (unsigned char)ti[0];
        }
        float bv = (lane < NT) ? sc + end_t[j] : -1e30f;
        int bi = (lane < NT) ? lane : NT;
#pragma unroll
        for (int off = 32; off >= 1; off >>= 1) {
            float ov = __shfl_xor(bv, off);
            int   oi = __shfl_xor(bi, off);
            if (ov > bv || (ov == bv && oi < bi)) { bv = ov; bi = oi; }
        }
        __syncthreads();
        if (lane == 0) {
            int tag = bi;
            crf_out[(size_t)b*SS + SS - 1] = (float)tag;
            for (int s = SS - 2; s >= 0; --s) {
                tag = hist[s*NT + tag];
                crf_out[(size_t)b*SS + s] = (float)tag;
            }
        }
    }
}

// =====================================================================
// Final scalar: -llh = -( sum_b(num[b]-den[b]) / 16384 )
// =====================================================================
__global__ __launch_bounds__(64) void llh_kernel(
    const float* __restrict__ num, const float* __restrict__ den,
    float* __restrict__ out)
{
    int t = threadIdx.x;
    float v = (t < BB) ? (num[t] - den[t]) : 0.f;
#pragma unroll
    for (int off = 32; off >= 1; off >>= 1) v += __shfl_xor(v, off);
    if (t == 0) out[(size_t)MR * 3] = -(v / (float)MR);
}

extern "C" void kernel_launch(void* const* d_in, const int* in_sizes, int n_in,
                              void* d_out, int out_size, void* d_ws, size_t ws_size,
                              hipStream_t stream) {
    const float* enc     = (const float*)d_in[0];
    const int*   labels  = (const int*)  d_in[1];
    // d_in[2] = mask (all ones by construction; unused)
    const float* Win     = (const float*)d_in[3];
    const float* bin     = (const float*)d_in[4];
    const float* Wout    = (const float*)d_in[5];
    const float* bout    = (const float*)d_in[6];
    const float* crf_w   = (const float*)d_in[7];
    const float* crf_b   = (const float*)d_in[8];
    const float* start_t = (const float*)d_in[9];
    const float* end_t   = (const float*)d_in[10];
    const float* trans   = (const float*)d_in[11];
    const float* ent_w   = (const float*)d_in[12];
    const float* ent_b   = (const float*)d_in[13];
    float* out = (float*)d_out;

    // Workspace layout — byte-identical footprint to round 10 (169.4 MB):
    //  qkvp   : MR*E3 u32  (packed hl qkv)
    //  encp   : MR*EE u32  (packed enc; dead after qkv gemm) -> attnp
    //  big    : MR*EE f32  (scores fp32 -> packed P in place; later dec)
    //  fc,num,den
    u32*   qkvp = (u32*)d_ws;
    u32*   encp = qkvp + (size_t)MR * E3;     // aliases attnp
    u32*   attnp = encp;
    float* big  = (float*)(encp + (size_t)MR * EE);
    float* sch  = big;
    float* dec  = big;
    float* fc   = big + (size_t)MR * EE;
    float* num  = fc  + (size_t)MR * NT;
    float* den  = num + BB;

    dim3 blk(256);
    // 0. split enc -> packed
    split_pack<<<(MR*EE)/1024, blk, 0, stream>>>(enc, encp);
    // 1. qkv = enc @ Win^T + bin  (A packed, B fp32 weights, out packed)
    mfma_gemm_p<0,1><<<dim3(E3/128, MR/128, 1), blk, 0, stream>>>(
        encp, EE, 0, 0, 0,  Win, EE, 0, 0, 0,  bin,
        qkvp, E3, 0, 0, 0,  EE, 0);
    // 2. attention in two z-passes of 32 (b,h) pairs each
    for (int p = 0; p < 2; ++p) {
        int zoff = p * 32;
        // scores[z][m][n] = Q[m].K[n]   (A,B packed; out fp32)
        mfma_gemm_p<1,0><<<dim3(SS/128, SS/128, 32), blk, 0, stream>>>(
            qkvp,      E3, (long)SS*E3, HDD, zoff,
            qkvp + EE, E3, (long)SS*E3, HDD, zoff,
            nullptr,
            sch, SS, 2L*SS*SS, (long)SS*SS, 0,
            HDD, 0);
        softmax_split<<<(32*SS)/4, blk, 0, stream>>>(sch);
        // attn = P V   (A packed P, B packed K x N, out packed)
        mfma_gemm_p<2,1><<<dim3(HDD/128, SS/128, 32), blk, 0, stream>>>(
            (u32*)sch, SS, 2L*SS*SS, (long)SS*SS, 0,
            qkvp + 2*EE, E3, (long)SS*E3, HDD, zoff,
            nullptr,
            attnp, EE, (long)SS*EE, HDD, zoff,
            SS, 0);
    }
    // 3. dec = relu(attn @ Wout^T + bout)  (A packed, B fp32, out fp32)
    mfma_gemm_p<0,0><<<dim3(EE/128, MR/128, 1), blk, 0, stream>>>(
        attnp, EE, 0, 0, 0,  Wout, EE, 0, 0, 0,  bout,
        dec, EE, 0, 0, 0,  EE, 1);
    // 4. fc emissions
    fc_crf_kernel<<<MR/8, dim3(192), 0, stream>>>(dec, crf_w, crf_b, fc);
    // 5. CRF (forward+viterbi+numerator) + seg head, 64-thread blocks
    crf_seg_kernel<<<96 + MR, dim3(64), 0, stream>>>(
        fc, labels, start_t, end_t, trans, dec, ent_w, ent_b,
        num, den, out, out + MR);
    // 6. -llh scalar -> d_out[49152]
    llh_kernel<<<1, 64, 0, stream>>>(num, den, out);
}

// Round 12
// 565.781 us; speedup vs baseline: 1.0553x; 1.0553x over previous
//
#include <hip/hip_runtime.h>

#define BB 32
#define SS 512
#define EE 512
#define NHH 2
#define HDD 256
#define E3 1536
#define NT 24
#define MR (BB*SS)   // 16384

typedef _Float16 half8  __attribute__((ext_vector_type(8)));
typedef _Float16 half4v __attribute__((ext_vector_type(4)));
typedef float    f32x4  __attribute__((ext_vector_type(4)));

// scalar (SGPR) lane broadcast — index MUST be wave-uniform (constant).
__device__ __forceinline__ float rl(float v, int l) {
    return __int_as_float(__builtin_amdgcn_readlane(__float_as_int(v), l));
}

// Raw barrier: lgkmcnt(0)-only drain (LDS ordering) WITHOUT vmcnt(0) —
// keeps prefetched global loads in flight across the barrier.
// (__syncthreads emits s_waitcnt vmcnt(0) lgkmcnt(0) which drains the
// prefetch every iteration — the round-11 diagnosed stall.)
#define LDS_BARRIER() __asm__ __volatile__("s_waitcnt lgkmcnt(0)\ns_barrier" ::: "memory")

// =====================================================================
// fp32-accurate GEMM via fp16 3-product MFMA split (Ootomo).
// 128x128 tile, 256 thr = 2x2 waves, 4x4 tiles of mfma 16x16x32 f16.
// BN=0: B row-major N x K (B^T form). BN=1: B row-major K x N (V).
// K-loop software-pipelined: loads for iter k+1 issue after staging of
// iter k; raw lgkm-only barriers keep them in flight through the MFMA
// section (register staging needs no cross-wave visibility).
// =====================================================================
template<int BN>
__global__ __launch_bounds__(256) void mfma_gemm(
    const float* __restrict__ A, int lda, long sAhi, long sAlo, int zA,
    const float* __restrict__ B, int ldb, long sBhi, long sBlo, int zB,
    const float* __restrict__ bias,
    float* __restrict__ C, int ldc, long sChi, long sClo, int zC,
    int K, int relu)
{
    __shared__ __align__(16) _Float16 sAh[8*640];
    __shared__ __align__(16) _Float16 sAl[8*640];
    __shared__ __align__(16) _Float16 sBh[8*640];
    __shared__ __align__(16) _Float16 sBl[8*640];

    const int t = threadIdx.x;
    const int z = blockIdx.z;
    const int za = zA + z, zb = zB + z, zc = zC + z;
    const float* Ab = A + (size_t)(za>>1)*sAhi + (size_t)(za&1)*sAlo
                        + (size_t)blockIdx.y*128*lda;
    const float* Bb = B + (size_t)(zb>>1)*sBhi + (size_t)(zb&1)*sBlo
                        + (BN ? (size_t)blockIdx.x*128
                              : (size_t)blockIdx.x*128*ldb);

    const int wv = t >> 6, lane = t & 63;
    const int wm = wv >> 1, wn = wv & 1;
    const int lm = lane & 15, lq = lane >> 4;

    f32x4 acc[4][4];
#pragma unroll
    for (int i = 0; i < 4; ++i)
#pragma unroll
        for (int j = 0; j < 4; ++j) acc[i][j] = (f32x4){0.f,0.f,0.f,0.f};

    const int r8  = t >> 3;         // 0..31 (staging row base)
    const int kc  = (t & 7) * 4;    // 0..28 (staging k chunk)
    const int bnk = (t >> 7) * 16;  // BN staging: k half
    const int bnn = t & 127;        // BN staging: n

    float4 ga[4], gb[4]; float gv[16];
    // ---- prologue: load K-chunk 0 ----
#pragma unroll
    for (int i = 0; i < 4; ++i)
        ga[i] = *(const float4*)(Ab + (size_t)(r8 + 32*i)*lda + kc);
    if (BN) {
#pragma unroll
        for (int i = 0; i < 16; ++i)
            gv[i] = Bb[(size_t)(bnk + i)*ldb + bnn];
    } else {
#pragma unroll
        for (int i = 0; i < 4; ++i)
            gb[i] = *(const float4*)(Bb + (size_t)(r8 + 32*i)*ldb + kc);
    }

    for (int k0 = 0; k0 < K; k0 += 32) {
        LDS_BARRIER();   // all waves done reading LDS (prev iter); vm stays in flight
#pragma unroll
        for (int i = 0; i < 4; ++i) {
            const int row  = r8 + 32*i;
            const int base = (row >> 4)*640 + (row & 15)*40 + kc;
            float4 a = ga[i];   // compiler emits vmcnt wait here (data dep)
            _Float16 h0 = (_Float16)a.x, h1 = (_Float16)a.y,
                     h2 = (_Float16)a.z, h3 = (_Float16)a.w;
            _Float16 l0 = (_Float16)(a.x - (float)h0),
                     l1 = (_Float16)(a.y - (float)h1),
                     l2 = (_Float16)(a.z - (float)h2),
                     l3 = (_Float16)(a.w - (float)h3);
            *(half4v*)&sAh[base] = (half4v){h0,h1,h2,h3};
            *(half4v*)&sAl[base] = (half4v){l0,l1,l2,l3};
        }
        if (BN) {
#pragma unroll
            for (int i = 0; i < 16; ++i) {
                const int k = bnk + i;
                float v = gv[i];
                _Float16 h = (_Float16)v;
                _Float16 l = (_Float16)(v - (float)h);
                const int base = (bnn >> 4)*640 + (bnn & 15)*40 + k;
                sBh[base] = h;
                sBl[base] = l;
            }
        } else {
#pragma unroll
            for (int i = 0; i < 4; ++i) {
                const int row  = r8 + 32*i;
                const int base = (row >> 4)*640 + (row & 15)*40 + kc;
                float4 b = gb[i];
                _Float16 h0 = (_Float16)b.x, h1 = (_Float16)b.y,
                         h2 = (_Float16)b.z, h3 = (_Float16)b.w;
                _Float16 l0 = (_Float16)(b.x - (float)h0),
                         l1 = (_Float16)(b.y - (float)h1),
                         l2 = (_Float16)(b.z - (float)h2),
                         l3 = (_Float16)(b.w - (float)h3);
                *(half4v*)&sBh[base] = (half4v){h0,h1,h2,h3};
                *(half4v*)&sBl[base] = (half4v){l0,l1,l2,l3};
            }
        }
        LDS_BARRIER();   // staging visible to all waves; vm stays in flight

        // ---- prefetch next K-chunk (clamped on last iter) ----
        const int kn = (k0 + 32 < K) ? (k0 + 32) : k0;
#pragma unroll
        for (int i = 0; i < 4; ++i)
            ga[i] = *(const float4*)(Ab + (size_t)(r8 + 32*i)*lda + kn + kc);
        if (BN) {
#pragma unroll
            for (int i = 0; i < 16; ++i)
                gv[i] = Bb[(size_t)(kn + bnk + i)*ldb + bnn];
        } else {
#pragma unroll
            for (int i = 0; i < 4; ++i)
                gb[i] = *(const float4*)(Bb + (size_t)(r8 + 32*i)*ldb + kn + kc);
        }

        // ---- MFMA section (hides the prefetch latency) ----
        half8 bhf[4], blf[4];
#pragma unroll
        for (int j = 0; j < 4; ++j) {
            const int tb = (wn*4 + j)*640 + lm*40 + lq*8;
            bhf[j] = *(const half8*)&sBh[tb];
            blf[j] = *(const half8*)&sBl[tb];
        }
#pragma unroll
        for (int i = 0; i < 4; ++i) {
            const int ta = (wm*4 + i)*640 + lm*40 + lq*8;
            half8 ah = *(const half8*)&sAh[ta];
            half8 al = *(const half8*)&sAl[ta];
#pragma unroll
            for (int j = 0; j < 4; ++j) {
                acc[i][j] = __builtin_amdgcn_mfma_f32_16x16x32_f16(ah, bhf[j], acc[i][j], 0, 0, 0);
                acc[i][j] = __builtin_amdgcn_mfma_f32_16x16x32_f16(al, bhf[j], acc[i][j], 0, 0, 0);
                acc[i][j] = __builtin_amdgcn_mfma_f32_16x16x32_f16(ah, blf[j], acc[i][j], 0, 0, 0);
            }
        }
    }

    // epilogue: C/D layout col = lane&15, row = quad*4 + reg
    float* Cb = C + (size_t)(zc>>1)*sChi + (size_t)(zc&1)*sClo;
#pragma unroll
    for (int j = 0; j < 4; ++j) {
        const int col = blockIdx.x*128 + (wn*4 + j)*16 + lm;
        const float bj = bias ? bias[col] : 0.f;
#pragma unroll
        for (int i = 0; i < 4; ++i) {
            const int row0 = blockIdx.y*128 + (wm*4 + i)*16 + lq*4;
#pragma unroll
            for (int r = 0; r < 4; ++r) {
                float v = acc[i][j][r] + bj;
                if (relu) v = fmaxf(v, 0.f);
                Cb[(size_t)(row0 + r)*ldc + col] = v;
            }
        }
    }
}

// =====================================================================
// Row softmax over scores (in place, fully normalized).
// =====================================================================
__global__ __launch_bounds__(256) void softmax_rows(float* __restrict__ scores)
{
    const int w    = threadIdx.x >> 6;
    const int lane = threadIdx.x & 63;
    const size_t row = (size_t)blockIdx.x * 4 + w;
    float* p = scores + row * SS + lane * 8;
    float4 v0 = *(float4*)(p);
    float4 v1 = *(float4*)(p + 4);
    const float scale = 0.0625f;
    float m = fmaxf(fmaxf(fmaxf(v0.x, v0.y), fmaxf(v0.z, v0.w)),
                    fmaxf(fmaxf(v1.x, v1.y), fmaxf(v1.z, v1.w)));
#pragma unroll
    for (int off = 32; off >= 1; off >>= 1) m = fmaxf(m, __shfl_xor(m, off));
    v0.x = __expf((v0.x - m) * scale); v0.y = __expf((v0.y - m) * scale);
    v0.z = __expf((v0.z - m) * scale); v0.w = __expf((v0.w - m) * scale);
    v1.x = __expf((v1.x - m) * scale); v1.y = __expf((v1.y - m) * scale);
    v1.z = __expf((v1.z - m) * scale); v1.w = __expf((v1.w - m) * scale);
    float sum = v0.x + v0.y + v0.z + v0.w + v1.x + v1.y + v1.z + v1.w;
#pragma unroll
    for (int off = 32; off >= 1; off >>= 1) sum += __shfl_xor(sum, off);
    float inv = 1.f / sum;
    v0.x *= inv; v0.y *= inv; v0.z *= inv; v0.w *= inv;
    v1.x *= inv; v1.y *= inv; v1.z *= inv; v1.w *= inv;
    *(float4*)(p)     = v0;
    *(float4*)(p + 4) = v1;
}

// =====================================================================
// CRF emissions: fc[row][j] = dot(dec[row], crf_w[j]) + crf_b[j]
// =====================================================================
__global__ __launch_bounds__(192) void fc_crf_kernel(
    const float* __restrict__ dec, const float* __restrict__ W,
    const float* __restrict__ bias, float* __restrict__ out)
{
    __shared__ __align__(16) float Ws[NT][516];
    for (int i = threadIdx.x; i < NT*128; i += 192) {
        int j = i >> 7, c = (i & 127) * 4;
        *(float4*)&Ws[j][c] = *(const float4*)(W + (size_t)j*EE + c);
    }
    __syncthreads();
    const int t = threadIdx.x;
    const int rloc = t / NT;
    const int j = t - rloc * NT;
    const int row = blockIdx.x * 8 + rloc;
    const float4* a = (const float4*)(dec + (size_t)row * EE);
    float acc = 0.f;
#pragma unroll 4
    for (int i = 0; i < 128; ++i) {
        float4 x = a[i];
        float4 y = *(const float4*)&Ws[j][i*4];
        acc += x.x*y.x + x.y*y.y + x.z*y.z + x.w*y.w;
    }
    out[(size_t)row * NT + j] = acc + bias[j];
}

// =====================================================================
// CRF + seg, 64-thread blocks (round-10 structure; serial legs are
// dependency-chain-bound — r9/r10 experiments showed memory is not the
// limiter).
// =====================================================================
__global__ __launch_bounds__(64, 1) void crf_seg_kernel(
    const float* __restrict__ fc, const int* __restrict__ labels,
    const float* __restrict__ start_t, const float* __restrict__ end_t,
    const float* __restrict__ trans, const float* __restrict__ dec,
    const float* __restrict__ ent_w, const float* __restrict__ ent_b,
    float* __restrict__ num, float* __restrict__ den,
    float* __restrict__ crf_out, float* __restrict__ segout)
{
    __shared__ __align__(16) float fc_lds[SS*NT];     // 48 KB
    __shared__ unsigned char hist[(SS-1)*NT];         // 12 KB

    const int blk  = blockIdx.x;
    const int lane = threadIdx.x;

    if (blk >= 96) {
        const int row = blk - 96;
        const float4* a  = (const float4*)(dec + (size_t)row * EE);
        const float4* w0 = (const float4*)(ent_w);
        const float4* w1 = (const float4*)(ent_w + EE);
        float acc0 = 0.f, acc1 = 0.f;
#pragma unroll
        for (int i = 0; i < 2; ++i) {
            int idx = lane * 2 + i;
            float4 x = a[idx];
            float4 u = w0[idx];
            float4 v = w1[idx];
            acc0 += x.x*u.x + x.y*u.y + x.z*u.z + x.w*u.w;
            acc1 += x.x*v.x + x.y*v.y + x.z*v.z + x.w*v.w;
        }
#pragma unroll
        for (int off = 32; off >= 1; off >>= 1) {
            acc0 += __shfl_xor(acc0, off);
            acc1 += __shfl_xor(acc1, off);
        }
        if (lane == 0) {
            float l0 = acc0 + ent_b[0];
            float l1 = acc1 + ent_b[1];
            float m  = fmaxf(l0, l1);
            float lse = m + __logf(__expf(l0 - m) + __expf(l1 - m));
            segout[(size_t)row*2 + 0] = l0 - lse;
            segout[(size_t)row*2 + 1] = l1 - lse;
        }
        return;
    }

    const int role = blk >> 5;          // 0=forward, 1=viterbi, 2=numerator
    const int b    = blk & 31;
    const float* fcb = fc + (size_t)b * SS * NT;

    if (role == 2) {
        float acc = 0.f;
        for (int s = 1 + lane; s < SS; s += 64) {
            int prev = labels[b*SS + s - 1];
            int cur  = labels[b*SS + s];
            acc += trans[prev*NT + cur] + fcb[(size_t)s*NT + cur];
        }
        if (lane == 0) {
            int l0 = labels[b*SS];
            acc += start_t[l0] + fcb[l0] + end_t[labels[b*SS + SS - 1]];
        }
#pragma unroll
        for (int off = 32; off >= 1; off >>= 1) acc += __shfl_xor(acc, off);
        if (lane == 0) num[b] = acc;
        return;
    }

#pragma unroll
    for (int i = 0; i < SS*NT/256; ++i) {
        const int idx = i*256 + lane*4;
        *(float4*)&fc_lds[idx] = *(const float4*)(fcb + idx);
    }
    __syncthreads();

    const int j = (lane < NT) ? lane : 0;
    float sc = start_t[j] + fc_lds[j];

    if (role == 0) {
        float etr[NT];
#pragma unroll
        for (int i = 0; i < NT; ++i) etr[i] = __expf(trans[i*NT + j]);
        float em_next = fc_lds[NT + j];
        for (int s = 1; s < SS; ++s) {
            float em = em_next;
            int snx = (s + 1 < SS) ? s + 1 : s;
            em_next = fc_lds[snx * NT + j];
            const float m  = __builtin_amdgcn_readfirstlane(sc);
            const float eo = __expf(sc - m);
            float a0 = 0.f, a1 = 0.f, a2 = 0.f, a3 = 0.f;
#pragma unroll
            for (int i = 0; i < NT; i += 4) {
                a0 = fmaf(rl(eo, i+0), etr[i+0], a0);
                a1 = fmaf(rl(eo, i+1), etr[i+1], a1);
                a2 = fmaf(rl(eo, i+2), etr[i+2], a2);
                a3 = fmaf(rl(eo, i+3), etr[i+3], a3);
            }
            sc = m + __logf((a0 + a1) + (a2 + a3)) + em;
        }
        float v = (lane < NT) ? sc + end_t[j] : -1e30f;
        float m2 = v;
#pragma unroll
        for (int off = 32; off >= 1; off >>= 1) m2 = fmaxf(m2, __shfl_xor(m2, off));
        float e = (lane < NT) ? __expf(v - m2) : 0.f;
#pragma unroll
        for (int off = 32; off >= 1; off >>= 1) e += __shfl_xor(e, off);
        if (lane == 0) den[b] = m2 + __logf(e);
    } else {
        float trC[NT];
#pragma unroll
        for (int i = 0; i < NT; ++i) trC[i] = trans[i*NT + j];
        float em_next = fc_lds[NT + j];
        for (int s = 1; s < SS; ++s) {
            float em = em_next;
            int snx = (s + 1 < SS) ? s + 1 : s;
            em_next = fc_lds[snx * NT + j];
            float tv[NT]; int ti[NT];
#pragma unroll
            for (int i = 0; i < NT; ++i) { tv[i] = rl(sc, i) + trC[i]; ti[i] = i; }
#pragma unroll
            for (int st = 1; st < NT; st <<= 1)
#pragma unroll
                for (int i = 0; i + st < NT; i += 2*st)
                    if (tv[i+st] > tv[i]) { tv[i] = tv[i+st]; ti[i] = ti[i+st]; }
            sc = tv[0] + em;
            if (lane < NT) hist[(s-1)*NT + lane] = (unsigned char)ti[0];
        }
        float bv = (lane < NT) ? sc + end_t[j] : -1e30f;
        int bi = (lane < NT) ? lane : NT;
#pragma unroll
        for (int off = 32; off >= 1; off >>= 1) {
            float ov = __shfl_xor(bv, off);
            int   oi = __shfl_xor(bi, off);
            if (ov > bv || (ov == bv && oi < bi)) { bv = ov; bi = oi; }
        }
        __syncthreads();
        if (lane == 0) {
            int tag = bi;
            crf_out[(size_t)b*SS + SS - 1] = (float)tag;
            for (int s = SS - 2; s >= 0; --s) {
                tag = hist[s*NT + tag];
                crf_out[(size_t)b*SS + s] = (float)tag;
            }
        }
    }
}

// =====================================================================
// Final scalar: -llh = -( sum_b(num[b]-den[b]) / 16384 )
// =====================================================================
__global__ __launch_bounds__(64) void llh_kernel(
    const float* __restrict__ num, const float* __restrict__ den,
    float* __restrict__ out)
{
    int t = threadIdx.x;
    float v = (t < BB) ? (num[t] - den[t]) : 0.f;
#pragma unroll
    for (int off = 32; off >= 1; off >>= 1) v += __shfl_xor(v, off);
    if (t == 0) out[(size_t)MR * 3] = -(v / (float)MR);
}

extern "C" void kernel_launch(void* const* d_in, const int* in_sizes, int n_in,
                              void* d_out, int out_size, void* d_ws, size_t ws_size,
                              hipStream_t stream) {
    const float* enc     = (const float*)d_in[0];
    const int*   labels  = (const int*)  d_in[1];
    // d_in[2] = mask (all ones by construction; unused)
    const float* Win     = (const float*)d_in[3];
    const float* bin     = (const float*)d_in[4];
    const float* Wout    = (const float*)d_in[5];
    const float* bout    = (const float*)d_in[6];
    const float* crf_w   = (const float*)d_in[7];
    const float* crf_b   = (const float*)d_in[8];
    const float* start_t = (const float*)d_in[9];
    const float* end_t   = (const float*)d_in[10];
    const float* trans   = (const float*)d_in[11];
    const float* ent_w   = (const float*)d_in[12];
    const float* ent_b   = (const float*)d_in[13];
    float* out = (float*)d_out;

    // Workspace layout — scores half (33.5 MB) aliases dec; scores are
    // dead before dec is written. (round-10 proven layout)
    float* ws   = (float*)d_ws;
    float* qkv  = ws;                                 // 16384*1536
    float* attn = qkv  + (size_t)MR * E3;             // 16384*512
    float* big  = attn + (size_t)MR * EE;             // 8,388,608 floats
    float* sch  = big;                                // scores half: 32*512*512
    float* dec  = big;                                // dec aliases scores
    float* fc   = big  + (size_t)MR * EE;             // 16384*24
    float* num  = fc   + (size_t)MR * NT;             // 32
    float* den  = num  + BB;                          // 32

    dim3 blk(256);
    // 1. qkv = enc @ Win^T + bin
    mfma_gemm<0><<<dim3(E3/128, MR/128, 1), blk, 0, stream>>>(
        enc, EE, 0, 0, 0,  Win, EE, 0, 0, 0,  bin,
        qkv, E3, 0, 0, 0,  EE, 0);
    // 2. attention in two z-passes of 32 (b,h) pairs each
    for (int p = 0; p < 2; ++p) {
        int zoff = p * 32;
        // scores[z][m][n] = Q[m].K[n]
        mfma_gemm<0><<<dim3(SS/128, SS/128, 32), blk, 0, stream>>>(
            qkv,      E3, (long)SS*E3, HDD, zoff,
            qkv + EE, E3, (long)SS*E3, HDD, zoff,
            nullptr,
            sch, SS, 2L*SS*SS, (long)SS*SS, 0,
            HDD, 0);
        softmax_rows<<<(32*SS)/4, blk, 0, stream>>>(sch);
        // attn[b,m,h*256+n] = sum_k P[z][m][k] V[b,k,h][n]
        mfma_gemm<1><<<dim3(HDD/128, SS/128, 32), blk, 0, stream>>>(
            sch, SS, 2L*SS*SS, (long)SS*SS, 0,
            qkv + 2*EE, E3, (long)SS*E3, HDD, zoff,
            nullptr,
            attn, EE, (long)SS*EE, HDD, zoff,
            SS, 0);
    }
    // 3. dec = relu(attn @ Wout^T + bout)   (overwrites scores region)
    mfma_gemm<0><<<dim3(EE/128, MR/128, 1), blk, 0, stream>>>(
        attn, EE, 0, 0, 0,  Wout, EE, 0, 0, 0,  bout,
        dec, EE, 0, 0, 0,  EE, 1);
    // 4. fc emissions
    fc_crf_kernel<<<MR/8, dim3(192), 0, stream>>>(dec, crf_w, crf_b, fc);
    // 5. CRF (forward+viterbi+numerator) + seg head, 64-thread blocks
    crf_seg_kernel<<<96 + MR, dim3(64), 0, stream>>>(
        fc, labels, start_t, end_t, trans, dec, ent_w, ent_b,
        num, den, out, out + MR);
    // 6. -llh scalar -> d_out[49152]
    llh_kernel<<<1, 64, 0, stream>>>(num, den, out);
}